// Round 14
// baseline (276.453 us; speedup 1.0000x reference)
//
#include <hip/hip_runtime.h>

#define EPSF 1e-5f
#define DECAYF 0.99f
#define KCODES 2048
#define DIM 256

typedef _Float16 f16;
typedef f16 f16x8 __attribute__((ext_vector_type(8)));
typedef float f32x4 __attribute__((ext_vector_type(4)));

#define MFMA16(A, B, C) __builtin_amdgcn_mfma_f32_16x16x32_f16(A, B, C, 0, 0, 0)

#define OFF_AH 0
#define OFF_AL 16384
#define OFF_BH 32768
#define OFF_BL 49152

__device__ __forceinline__ void gload_lds16(const void* g, void* l) {
    __builtin_amdgcn_global_load_lds(
        (const __attribute__((address_space(1))) void*)g,
        (__attribute__((address_space(3))) void*)l, 16, 0, 0);
}

// ---------------------------------------------------------------------------
// fused split_x + prep_embed + zero(sums,cnt); stats via 64-slot partial
// atomics. Order-preserving uint keys, both atomicMax, both init 0x00000000:
//   maxx2 key = u(x2) | 0x80000000 ; mine2 key = ~u(-e2)
// ---------------------------------------------------------------------------
__global__ __launch_bounds__(256) void split_prep_kernel(
    const float* __restrict__ x, f16* __restrict__ xh, f16* __restrict__ xl, int nsplit,
    const float* __restrict__ embed_sum, const float* __restrict__ usage,
    float* __restrict__ embed, f16* __restrict__ eh, f16* __restrict__ el,
    float* __restrict__ e2, unsigned* __restrict__ pmax, unsigned* __restrict__ pmin,
    float* __restrict__ sums, int* __restrict__ cnt)
{
    if ((int)blockIdx.x < nsplit) {
        int i = blockIdx.x * 256 + threadIdx.x;
        f32x4 v0 = ((const f32x4*)x)[2 * i];
        f32x4 v1 = ((const f32x4*)x)[2 * i + 1];
        f16x8 h, l;
        float p = 0.f;
        #pragma unroll
        for (int t = 0; t < 4; ++t) {
            f16 h0 = (f16)v0[t]; h[t] = h0; l[t] = (f16)(v0[t] - (float)h0);
            f16 h1 = (f16)v1[t]; h[t + 4] = h1; l[t + 4] = (f16)(v1[t] - (float)h1);
            p += v0[t] * v0[t] + v1[t] * v1[t];
        }
        ((f16x8*)xh)[i] = h;
        ((f16x8*)xl)[i] = l;
        #pragma unroll
        for (int m = 1; m <= 16; m <<= 1) p += __shfl_xor(p, m, 64);
        float q = fmaxf(p, __shfl_xor(p, 32, 64));
        __shared__ float wmax[4];
        if ((threadIdx.x & 63) == 0) wmax[threadIdx.x >> 6] = q;
        __syncthreads();
        if (threadIdx.x == 0) {
            float bm = fmaxf(fmaxf(wmax[0], wmax[1]), fmaxf(wmax[2], wmax[3]));
            atomicMax(&pmax[blockIdx.x & 63], __float_as_uint(bm) | 0x80000000u);
        }
    } else if ((int)blockIdx.x < nsplit + KCODES) {
        int k = blockIdx.x - nsplit;
        int d = threadIdx.x;
        float inv = 1.0f / fmaxf(usage[k], EPSF);
        float e = embed_sum[k * DIM + d] * inv;
        embed[k * DIM + d] = e;
        float ec = fminf(fmaxf(e, -65000.0f), 65000.0f);
        f16 h = (f16)ec;
        f16 l = (f16)(ec - (float)h);
        eh[k * DIM + d] = h;
        el[k * DIM + d] = l;
        float sq = e * e;
        #pragma unroll
        for (int off = 32; off > 0; off >>= 1) sq += __shfl_down(sq, off, 64);
        __shared__ float ws[4];
        if ((threadIdx.x & 63) == 0) ws[threadIdx.x >> 6] = sq;
        __syncthreads();
        if (threadIdx.x == 0) {
            float s = ws[0] + ws[1] + ws[2] + ws[3];
            e2[k] = s;
            atomicMax(&pmin[k & 63], ~__float_as_uint(-s));
        }
    } else {
        int k = blockIdx.x - nsplit - KCODES;
        sums[k * DIM + threadIdx.x] = 0.f;
        if (threadIdx.x == 0) cnt[k] = 0;
    }
}

// ---------------------------------------------------------------------------
// compactA: reduce 64-slot stats -> exact prune threshold; STABLE compaction
// (1 block). Winner bound: ||e_k|| <= 2*max||x|| + min||e||.
// ---------------------------------------------------------------------------
__global__ __launch_bounds__(256) void compactA_kernel(
    const float* __restrict__ e2, const unsigned* __restrict__ pmax,
    const unsigned* __restrict__ pmin, float* __restrict__ ce2,
    int* __restrict__ cmap, int* __restrict__ meta)
{
    __shared__ int ps[256];
    __shared__ float sT;
    const int t = threadIdx.x;
    if (t < 64) {
        unsigned km = pmax[t], kn = pmin[t];
        #pragma unroll
        for (int m = 1; m <= 32; m <<= 1) {
            km = max(km, (unsigned)__shfl_xor((int)km, m, 64));
            kn = max(kn, (unsigned)__shfl_xor((int)kn, m, 64));
        }
        if (t == 0) {
            float mx = __uint_as_float(km & 0x7FFFFFFFu);
            float mn = -__uint_as_float(~kn);
            float T0 = 2.0f * sqrtf(mx) + sqrtf(mn);
            sT = T0 * T0 * 1.0002f + 1.0f;
        }
    }
    __syncthreads();
    const float T = sT;
    int flag[8], pre[8], s = 0;
    float ev[8];
    #pragma unroll
    for (int j = 0; j < 8; ++j) {
        ev[j] = e2[t * 8 + j];
        flag[j] = (ev[j] <= T) ? 1 : 0;
        pre[j] = s; s += flag[j];
    }
    ps[t] = s;
    __syncthreads();
    for (int off = 1; off < 256; off <<= 1) {
        int v = (t >= off) ? ps[t - off] : 0;
        __syncthreads();
        ps[t] += v;
        __syncthreads();
    }
    const int ex = (t > 0) ? ps[t - 1] : 0;
    const int kp = ps[255];
    #pragma unroll
    for (int j = 0; j < 8; ++j) {
        const int k = t * 8 + j;
        if (flag[j]) {
            const int p = ex + pre[j];
            ce2[p] = ev[j];
            cmap[p] = k;
        }
    }
    for (int j = t; j < KCODES; j += 256)
        if (j >= kp) { ce2[j] = 3.4e38f; cmap[j] = 0; }
    if (t == 0) { meta[0] = kp; meta[1] = (kp + 255) & ~255; }
}

// ---------------------------------------------------------------------------
// argmin over the pruned codebook (round-12 version: best measured 162us).
// ds_reads issue FIRST (pinned via sched_barrier), staging after (latency
// hides under the 96-MFMA window), indirect B rows via in-stage cmap loads.
// ---------------------------------------------------------------------------
__global__ __launch_bounds__(512, 2) void argmin_kernel(
    const f16* __restrict__ xh, const f16* __restrict__ xl,
    const f16* __restrict__ eh, const f16* __restrict__ el,
    const float* __restrict__ ce2, const int* __restrict__ cmap,
    const int* __restrict__ meta, int* __restrict__ flat_ind, int* __restrict__ cnt)
{
    __shared__ __align__(1024) char lds[2 * 65536 + 8192];
    float* e2s = (float*)(lds + 131072);

    const int ncc = meta[1] >> 5;
    const int tid  = threadIdx.x;
    const int w    = tid >> 6, lane = tid & 63;
    const int l15  = lane & 15, l4 = lane >> 4;
    const int wm   = w >> 1, wn = w & 1;
    const int row0 = blockIdx.x * 256;
    const int gsw  = (lane & 3) ^ ((lane >> 3) & 3);
    const int lq   = lane >> 2;
    const int rslot = (l4 ^ ((l15 >> 1) & 3)) * 16;

    f32x4 acc[4][8];
    float best[16];
    int   bidx[16];
    #pragma unroll
    for (int t = 0; t < 16; ++t) { best[t] = 3.4e38f; bidx[t] = 0; }

    auto stageA = [&](const f16* rowbase, int koff, char* unit) {
        #pragma unroll
        for (int q = 0; q < 2; ++q) {
            const int r = w * 32 + q * 16 + lq;
            gload_lds16(rowbase + (size_t)r * DIM + koff + gsw * 8,
                        unit + w * 2048 + q * 1024 + lane * 16);
        }
    };
    auto stageB = [&](int tileBase, int koff, char* unitH, char* unitL) {
        #pragma unroll
        for (int q = 0; q < 2; ++q) {
            const int r = w * 32 + q * 16 + lq;
            const int pr = cmap[tileBase + r];
            gload_lds16(eh + (size_t)pr * DIM + koff + gsw * 8,
                        unitH + w * 2048 + q * 1024 + lane * 16);
            gload_lds16(el + (size_t)pr * DIM + koff + gsw * 8,
                        unitL + w * 2048 + q * 1024 + lane * 16);
        }
    };

    ((f32x4*)e2s)[tid] = ((const f32x4*)ce2)[tid];
    stageA(xh + (size_t)row0 * DIM, 0, lds + OFF_AH);
    stageA(xl + (size_t)row0 * DIM, 0, lds + OFF_AL);
    stageB(0, 0, lds + OFF_BH, lds + OFF_BL);

    for (int cc = 0; cc < ncc; ++cc) {
        char* buf  = lds + (cc & 1) * 65536;
        char* nbuf = lds + ((cc + 1) & 1) * 65536;
        const int ct = cc >> 3, sd = cc & 7;
        const int nn = cc + 1;
        const int nct = nn >> 3, nsd = nn & 7;
        const bool more = (nn < ncc);

        if (sd == 0) {
            #pragma unroll
            for (int i = 0; i < 4; ++i)
                #pragma unroll
                for (int j = 0; j < 8; ++j)
                    acc[i][j] = (f32x4){0.f, 0.f, 0.f, 0.f};
        }

        asm volatile("s_waitcnt vmcnt(0)" ::: "memory");
        __builtin_amdgcn_s_barrier();
        __builtin_amdgcn_sched_barrier(0);

        // ---- reads FIRST: ah + bh (12 x ds_read_b128), pinned before stage
        f16x8 ah[4], al[4], bh[8], bl[8];
        #pragma unroll
        for (int i = 0; i < 4; ++i)
            ah[i] = *(const f16x8*)(buf + OFF_AH + (wm * 64 + i * 16 + l15) * 64 + rslot);
        #pragma unroll
        for (int j = 0; j < 8; ++j)
            bh[j] = *(const f16x8*)(buf + OFF_BH + (wn * 128 + j * 16 + l15) * 64 + rslot);
        __builtin_amdgcn_sched_barrier(0);

        // ---- stage next chunk (latency hides under the MFMA window below)
        if (more) {
            stageA(xh + (size_t)row0 * DIM, nsd * 32, nbuf + OFF_AH);
            stageA(xl + (size_t)row0 * DIM, nsd * 32, nbuf + OFF_AL);
            stageB(nct * 256, nsd * 32, nbuf + OFF_BH, nbuf + OFF_BL);
        }

        // ---- MFMA pass 1: ah * bh
        #pragma unroll
        for (int i = 0; i < 4; ++i)
            #pragma unroll
            for (int j = 0; j < 8; ++j)
                acc[i][j] = MFMA16(ah[i], bh[j], acc[i][j]);

        // ---- pass 2: al * bh
        #pragma unroll
        for (int i = 0; i < 4; ++i)
            al[i] = *(const f16x8*)(buf + OFF_AL + (wm * 64 + i * 16 + l15) * 64 + rslot);
        #pragma unroll
        for (int i = 0; i < 4; ++i)
            #pragma unroll
            for (int j = 0; j < 8; ++j)
                acc[i][j] = MFMA16(al[i], bh[j], acc[i][j]);

        // ---- pass 3: ah * bl
        #pragma unroll
        for (int j = 0; j < 8; ++j)
            bl[j] = *(const f16x8*)(buf + OFF_BL + (wn * 128 + j * 16 + l15) * 64 + rslot);
        #pragma unroll
        for (int i = 0; i < 4; ++i)
            #pragma unroll
            for (int j = 0; j < 8; ++j)
                acc[i][j] = MFMA16(ah[i], bl[j], acc[i][j]);

        if (sd == 7) {
            const int cbase = ct * 256 + wn * 128;
            #pragma unroll
            for (int j = 0; j < 8; ++j) {
                const int col = cbase + j * 16 + l15;
                const float e2v = e2s[col];
                #pragma unroll
                for (int i = 0; i < 4; ++i)
                    #pragma unroll
                    for (int r = 0; r < 4; ++r) {
                        float m = fmaf(-2.0f, acc[i][j][r], e2v);
                        const int tt_ = i * 4 + r;
                        if (m < best[tt_]) { best[tt_] = m; bidx[tt_] = col; }
                    }
            }
        }
    }

    __syncthreads();
    float* rv = (float*)lds;
    int*   ri = (int*)(lds + 4096);
    #pragma unroll
    for (int tt_ = 0; tt_ < 16; ++tt_) {
        float v = best[tt_];
        int  ix = bidx[tt_];
        #pragma unroll
        for (int m = 1; m <= 8; m <<= 1) {
            float ov = __shfl_xor(v, m, 64);
            int  oix = __shfl_xor(ix, m, 64);
            if (ov < v || (ov == v && oix < ix)) { v = ov; ix = oix; }
        }
        if (l15 == 0) {
            const int rl = wm * 64 + (tt_ >> 2) * 16 + l4 * 4 + (tt_ & 3);
            rv[rl * 2 + wn] = v;
            ri[rl * 2 + wn] = ix;
        }
    }
    __syncthreads();
    if (tid < 256) {
        float v0 = rv[tid * 2], v1 = rv[tid * 2 + 1];
        int   i0 = ri[tid * 2], i1 = ri[tid * 2 + 1];
        int ibc = (v1 < v0 || (v1 == v0 && i1 < i0)) ? i1 : i0;
        int ib = cmap[ibc];
        flat_ind[row0 + tid] = ib;
        unsigned long long pending = ~0ULL;
        while (pending) {
            int leader = __ffsll((long long)pending) - 1;
            int lind = __shfl(ib, leader, 64);
            unsigned long long same = __ballot(ib == lind);
            if ((tid & 63) == leader) atomicAdd(&cnt[lind], (int)__popcll(same));
            pending &= ~same;
        }
    }
}

// ---------------------------------------------------------------------------
// fused scan + quantize: block 0 does the 2048-count exclusive prefix sum
// (offs/cursor); blocks [1, 1+nq) stream out_q = embed[flat_ind] and
// out_ind — the serial scan hides under 128 MB of streaming.
// ---------------------------------------------------------------------------
__global__ __launch_bounds__(256) void scan_quant_kernel(
    const int* __restrict__ cnt, int* __restrict__ offs, int* __restrict__ cursor,
    const float* __restrict__ embed, const int* __restrict__ flat_ind,
    float* __restrict__ out_q, float* __restrict__ out_ind_f, int N)
{
    if (blockIdx.x == 0) {
        __shared__ int ps[256];
        const int t = threadIdx.x;
        int pre[8], s = 0;
        #pragma unroll
        for (int j = 0; j < 8; ++j) { pre[j] = s; s += cnt[t * 8 + j]; }
        ps[t] = s;
        __syncthreads();
        for (int off = 1; off < 256; off <<= 1) {
            int v = (t >= off) ? ps[t - off] : 0;
            __syncthreads();
            ps[t] += v;
            __syncthreads();
        }
        int ex = (t > 0) ? ps[t - 1] : 0;
        #pragma unroll
        for (int j = 0; j < 8; ++j) {
            offs[t * 8 + j]   = ex + pre[j];
            cursor[t * 8 + j] = ex + pre[j];
        }
    } else {
        int i = (blockIdx.x - 1) * 256 + threadIdx.x;   // over N*64 float4s
        int row = i >> 6, c4 = i & 63;
        int ind = flat_ind[row];
        ((f32x4*)out_q)[i] = ((const f32x4*)embed)[ind * 64 + c4];
        if (i < N) out_ind_f[i] = (float)flat_ind[i];
    }
}

// ---------------------------------------------------------------------------
// assign: counting-sort placement with wave-aggregated cursor atomics.
// ---------------------------------------------------------------------------
__global__ __launch_bounds__(256) void assign_kernel(
    const int* __restrict__ flat_ind, int* __restrict__ cursor,
    int* __restrict__ rowlist, int* __restrict__ codesorted)
{
    const int i    = blockIdx.x * 256 + threadIdx.x;
    const int lane = threadIdx.x & 63;
    const int ind  = flat_ind[i];
    int pos = 0;
    unsigned long long pending = ~0ULL;
    while (pending) {
        int leader = __ffsll((long long)pending) - 1;
        int lind = __shfl(ind, leader, 64);
        unsigned long long same = __ballot(ind == lind);
        if (ind == lind) {
            int base = 0;
            if (lane == leader) base = atomicAdd(&cursor[lind], (int)__popcll(same));
            base = __shfl(base, leader, 64);
            pos = base + (int)__popcll(same & ((1ULL << lane) - 1ULL));
        }
        pending &= ~same;
    }
    rowlist[pos] = i;
    codesorted[pos] = ind;
}

// ---------------------------------------------------------------------------
// codesum: pure chunked segmented reduction over sorted rows (skew-proof).
// ---------------------------------------------------------------------------
__global__ __launch_bounds__(256) void codesum_kernel(
    const float* __restrict__ x, const int* __restrict__ rowlist,
    const int* __restrict__ codesorted, float* __restrict__ sums)
{
    const int p0 = blockIdx.x * 64;
    __shared__ int rows[64], codes[64];
    if (threadIdx.x < 64) {
        rows[threadIdx.x]  = rowlist[p0 + threadIdx.x];
        codes[threadIdx.x] = codesorted[p0 + threadIdx.x];
    }
    __syncthreads();
    const int d = threadIdx.x;
    float acc = 0.f;
    int cur = codes[0];
    #pragma unroll 4
    for (int r = 0; r < 64; ++r) {
        const int c = codes[r];
        if (c != cur) {
            atomicAdd(&sums[(size_t)cur * DIM + d], acc);
            acc = 0.f; cur = c;
        }
        acc += x[(size_t)rows[r] * DIM + d];
    }
    atomicAdd(&sums[(size_t)cur * DIM + d], acc);
}

// ---------------------------------------------------------------------------
// finalize: EMA update outputs
// ---------------------------------------------------------------------------
__global__ __launch_bounds__(256) void finalize_kernel(
    const float* __restrict__ embed_sum, const float* __restrict__ usage,
    const float* __restrict__ sums, const int* __restrict__ cnt,
    float* __restrict__ out_usage, float* __restrict__ out_es)
{
    const int k = blockIdx.x, d = threadIdx.x;
    out_es[k * DIM + d] = embed_sum[k * DIM + d] * DECAYF + sums[k * DIM + d] * (1.0f - DECAYF);
    if (d == 0)
        out_usage[k] = usage[k] * DECAYF + (float)cnt[k] * (1.0f - DECAYF);
}

extern "C" void kernel_launch(void* const* d_in, const int* in_sizes, int n_in,
                              void* d_out, int out_size, void* d_ws, size_t ws_size,
                              hipStream_t stream)
{
    const float* hs        = (const float*)d_in[0];
    const float* embed_sum = (const float*)d_in[1];
    const float* usage     = (const float*)d_in[2];
    const int N = in_sizes[0] / DIM;   // 65536

    float* ws_f      = (float*)d_ws;
    float* embed     = ws_f;                         // K*D f32
    float* e2        = embed + KCODES * DIM;         // K
    float* sums      = e2 + KCODES;                  // K*D f32 (zeroed in split_prep)
    int*   cnt       = (int*)(sums + KCODES * DIM);  // K       (zeroed in split_prep)
    unsigned* pmax   = (unsigned*)(cnt + KCODES);    // 64  (memset 0)
    unsigned* pmin   = pmax + 64;                    // 64  (memset 0)
    f16*   eh        = (f16*)(pmin + 64);            // K*D f16
    f16*   el        = eh + KCODES * DIM;            // K*D f16
    float* ce2       = (float*)(el + KCODES * DIM);  // K
    int*   cmap      = (int*)(ce2 + KCODES);         // K
    int*   meta      = cmap + KCODES;                // 16
    int*   offs      = meta + 16;                    // K
    int*   cursor    = offs + KCODES;                // K
    int*   rowlist   = cursor + KCODES;              // N
    int*   codesorted= rowlist + N;                  // N
    int*   flat_ind  = codesorted + N;               // N

    float* out_q     = (float*)d_out;                // N*D
    float* out_ind   = out_q + (size_t)N * DIM;      // N
    float* out_usage = out_ind + N;                  // K
    float* out_es    = out_usage + KCODES;           // K*D

    // xh/xl live in the out_q region (exactly N*D*4B); dead after argmin,
    // scan_quant overwrites out_q afterwards.
    f16* xh = (f16*)out_q;
    f16* xl = xh + (size_t)N * DIM;

    hipMemsetAsync(pmax, 0, 128 * sizeof(unsigned), stream);

    const int nsplit = N * DIM / 8 / 256;            // 8192
    split_prep_kernel<<<nsplit + 2 * KCODES, 256, 0, stream>>>(
        hs, xh, xl, nsplit, embed_sum, usage, embed, eh, el, e2, pmax, pmin,
        sums, cnt);
    compactA_kernel<<<1, 256, 0, stream>>>(e2, pmax, pmin, ce2, cmap, meta);
    argmin_kernel<<<N / 256, 512, 0, stream>>>(xh, xl, eh, el, ce2, cmap, meta,
                                               flat_ind, cnt);
    const int nq = N * DIM / 4 / 256;                // 16384
    scan_quant_kernel<<<1 + nq, 256, 0, stream>>>(cnt, offs, cursor,
                                                  embed, flat_ind, out_q, out_ind, N);
    assign_kernel<<<N / 256, 256, 0, stream>>>(flat_ind, cursor, rowlist, codesorted);
    codesum_kernel<<<N / 64, 256, 0, stream>>>(hs, rowlist, codesorted, sums);
    finalize_kernel<<<KCODES, 256, 0, stream>>>(embed_sum, usage, sums, cnt,
                                                out_usage, out_es);
}

// Round 15
// 263.945 us; speedup vs baseline: 1.0474x; 1.0474x over previous
//
#include <hip/hip_runtime.h>

#define EPSF 1e-5f
#define DECAYF 0.99f
#define KCODES 2048
#define DIM 256

typedef _Float16 f16;
typedef f16 f16x8 __attribute__((ext_vector_type(8)));
typedef float f32x4 __attribute__((ext_vector_type(4)));

#define MFMA16(A, B, C) __builtin_amdgcn_mfma_f32_16x16x32_f16(A, B, C, 0, 0, 0)

#define OFF_AH 0
#define OFF_AL 16384
#define OFF_BH 32768
#define OFF_BL 49152

__device__ __forceinline__ void gload_lds16(const void* g, void* l) {
    __builtin_amdgcn_global_load_lds(
        (const __attribute__((address_space(1))) void*)g,
        (__attribute__((address_space(3))) void*)l, 16, 0, 0);
}

// ---------------------------------------------------------------------------
// prep: embed = embed_sum/clamp(usage); e2; saturated f16 split of embed;
// blocks [K,2K) zero sums/cnt (consumed only by later dispatches).
// ---------------------------------------------------------------------------
__global__ __launch_bounds__(256) void prep_kernel(
    const float* __restrict__ embed_sum, const float* __restrict__ usage,
    float* __restrict__ embed, f16* __restrict__ eh, f16* __restrict__ el,
    float* __restrict__ e2, float* __restrict__ sums, int* __restrict__ cnt)
{
    if ((int)blockIdx.x < KCODES) {
        int k = blockIdx.x;
        int d = threadIdx.x;
        float inv = 1.0f / fmaxf(usage[k], EPSF);
        float e = embed_sum[k * DIM + d] * inv;
        embed[k * DIM + d] = e;
        float ec = fminf(fmaxf(e, -65000.0f), 65000.0f);
        f16 h = (f16)ec;
        f16 l = (f16)(ec - (float)h);
        eh[k * DIM + d] = h;
        el[k * DIM + d] = l;
        float sq = e * e;
        #pragma unroll
        for (int off = 32; off > 0; off >>= 1) sq += __shfl_down(sq, off, 64);
        __shared__ float ws[4];
        if ((threadIdx.x & 63) == 0) ws[threadIdx.x >> 6] = sq;
        __syncthreads();
        if (threadIdx.x == 0) e2[k] = ws[0] + ws[1] + ws[2] + ws[3];
    } else {
        int k = blockIdx.x - KCODES;
        sums[k * DIM + threadIdx.x] = 0.f;
        if (threadIdx.x == 0) cnt[k] = 0;
    }
}

// ---------------------------------------------------------------------------
// pick: find the 8 smallest-e2 codes (indices + values), 1 block.
// Key = (u(e2)<<32)|k -> min = smallest e2, ties to smallest k.
// ---------------------------------------------------------------------------
__global__ __launch_bounds__(256) void pick_kernel(
    const float* __restrict__ e2, int* __restrict__ cidx, float* __restrict__ e2c)
{
    __shared__ unsigned long long red[256];
    const int t = threadIdx.x;
    unsigned long long local[8];
    #pragma unroll
    for (int j = 0; j < 8; ++j) {
        float v = e2[t * 8 + j];
        local[j] = ((unsigned long long)__float_as_uint(v) << 32) | (unsigned)(t * 8 + j);
    }
    for (int r = 0; r < 8; ++r) {
        unsigned long long m = ~0ULL;
        #pragma unroll
        for (int j = 0; j < 8; ++j) m = (local[j] < m) ? local[j] : m;
        red[t] = m;
        __syncthreads();
        for (int off = 128; off > 0; off >>= 1) {
            if (t < off) red[t] = (red[t + off] < red[t]) ? red[t + off] : red[t];
            __syncthreads();
        }
        unsigned long long g = red[0];
        __syncthreads();
        int k = (int)(g & 0xFFFFFFFFu);
        if (t == 0) { cidx[r] = k; e2c[r] = __uint_as_float((unsigned)(g >> 32)); }
        #pragma unroll
        for (int j = 0; j < 8; ++j)
            if ((int)(local[j] & 0xFFFFFFFFu) == k) local[j] = ~0ULL;
    }
}

// ---------------------------------------------------------------------------
// splitx: xh/xl split + per-row exact prune key:
//   key = (||x|| + min_{r<8} d(x,c_r))^2   (winner bound, rigorous)
// 64-slot partial atomicMax (key>0, encoded |0x80000000, init 0).
// ---------------------------------------------------------------------------
__global__ __launch_bounds__(256) void splitx_kernel(
    const float* __restrict__ x, f16* __restrict__ xh, f16* __restrict__ xl,
    const float* __restrict__ embed, const int* __restrict__ cidx,
    const float* __restrict__ e2c, unsigned* __restrict__ pmax)
{
    __shared__ float ecs[8 * 256];
    __shared__ float e2cs[8];
    __shared__ float wmax[4];
    const int t = threadIdx.x;
    #pragma unroll
    for (int j = 0; j < 8; ++j) {
        int idx = t * 8 + j;  // 0..2047
        ecs[idx] = embed[(size_t)cidx[idx >> 8] * DIM + (idx & 255)];
    }
    if (t < 8) e2cs[t] = e2c[t];
    __syncthreads();

    int i = blockIdx.x * 256 + t;
    f32x4 v0 = ((const f32x4*)x)[2 * i];
    f32x4 v1 = ((const f32x4*)x)[2 * i + 1];
    float xv[8];
    #pragma unroll
    for (int q = 0; q < 4; ++q) { xv[q] = v0[q]; xv[q + 4] = v1[q]; }
    f16x8 h, l;
    float p = 0.f;
    #pragma unroll
    for (int j = 0; j < 8; ++j) {
        f16 hh = (f16)xv[j]; h[j] = hh; l[j] = (f16)(xv[j] - (float)hh);
        p += xv[j] * xv[j];
    }
    ((f16x8*)xh)[i] = h;
    ((f16x8*)xl)[i] = l;

    const int base = (t & 31) * 8;
    float dot[8];
    #pragma unroll
    for (int r = 0; r < 8; ++r) {
        const float* er = &ecs[r * 256 + base];
        float d = 0.f;
        #pragma unroll
        for (int j = 0; j < 8; ++j) d = fmaf(xv[j], er[j], d);
        dot[r] = d;
    }
    // butterfly over the 32 lanes of each x-row
    #pragma unroll
    for (int m = 1; m <= 16; m <<= 1) {
        p += __shfl_xor(p, m, 64);
        #pragma unroll
        for (int r = 0; r < 8; ++r) dot[r] += __shfl_xor(dot[r], m, 64);
    }
    float dmin2 = 3.4e38f;
    #pragma unroll
    for (int r = 0; r < 8; ++r) {
        float d2 = fmaxf(fmaf(-2.f, dot[r], p) + e2cs[r], 0.f);
        dmin2 = fminf(dmin2, d2);
    }
    float key = sqrtf(p) + sqrtf(dmin2);
    key = key * key;
    #pragma unroll
    for (int m = 1; m <= 32; m <<= 1) key = fmaxf(key, __shfl_xor(key, m, 64));
    if ((t & 63) == 0) wmax[t >> 6] = key;
    __syncthreads();
    if (t == 0) {
        float bm = fmaxf(fmaxf(wmax[0], wmax[1]), fmaxf(wmax[2], wmax[3]));
        atomicMax(&pmax[blockIdx.x & 63], __float_as_uint(bm) | 0x80000000u);
    }
}

// ---------------------------------------------------------------------------
// compactA: T = max key (64-slot reduce) with fp slop; STABLE compaction.
// ---------------------------------------------------------------------------
__global__ __launch_bounds__(256) void compactA_kernel(
    const float* __restrict__ e2, const unsigned* __restrict__ pmax,
    float* __restrict__ ce2, int* __restrict__ cmap, int* __restrict__ meta)
{
    __shared__ int ps[256];
    __shared__ float sT;
    const int t = threadIdx.x;
    if (t < 64) {
        unsigned km = pmax[t];
        #pragma unroll
        for (int m = 1; m <= 32; m <<= 1)
            km = max(km, (unsigned)__shfl_xor((int)km, m, 64));
        if (t == 0) {
            float mx = __uint_as_float(km & 0x7FFFFFFFu);
            sT = mx * 1.0005f + 1.0f;
        }
    }
    __syncthreads();
    const float T = sT;
    int flag[8], pre[8], s = 0;
    float ev[8];
    #pragma unroll
    for (int j = 0; j < 8; ++j) {
        ev[j] = e2[t * 8 + j];
        flag[j] = (ev[j] <= T) ? 1 : 0;
        pre[j] = s; s += flag[j];
    }
    ps[t] = s;
    __syncthreads();
    for (int off = 1; off < 256; off <<= 1) {
        int v = (t >= off) ? ps[t - off] : 0;
        __syncthreads();
        ps[t] += v;
        __syncthreads();
    }
    const int ex = (t > 0) ? ps[t - 1] : 0;
    const int kp = ps[255];
    #pragma unroll
    for (int j = 0; j < 8; ++j) {
        const int k = t * 8 + j;
        if (flag[j]) {
            const int p = ex + pre[j];
            ce2[p] = ev[j];
            cmap[p] = k;
        }
    }
    for (int j = t; j < KCODES; j += 256)
        if (j >= kp) { ce2[j] = 3.4e38f; cmap[j] = 0; }
    if (t == 0) { meta[0] = kp; meta[1] = (kp + 255) & ~255; }
}

// ---------------------------------------------------------------------------
// argmin over the pruned codebook (round-12 version: best measured 162us).
// ---------------------------------------------------------------------------
__global__ __launch_bounds__(512, 2) void argmin_kernel(
    const f16* __restrict__ xh, const f16* __restrict__ xl,
    const f16* __restrict__ eh, const f16* __restrict__ el,
    const float* __restrict__ ce2, const int* __restrict__ cmap,
    const int* __restrict__ meta, int* __restrict__ flat_ind, int* __restrict__ cnt)
{
    __shared__ __align__(1024) char lds[2 * 65536 + 8192];
    float* e2s = (float*)(lds + 131072);

    const int ncc = meta[1] >> 5;
    const int tid  = threadIdx.x;
    const int w    = tid >> 6, lane = tid & 63;
    const int l15  = lane & 15, l4 = lane >> 4;
    const int wm   = w >> 1, wn = w & 1;
    const int row0 = blockIdx.x * 256;
    const int gsw  = (lane & 3) ^ ((lane >> 3) & 3);
    const int lq   = lane >> 2;
    const int rslot = (l4 ^ ((l15 >> 1) & 3)) * 16;

    f32x4 acc[4][8];
    float best[16];
    int   bidx[16];
    #pragma unroll
    for (int t = 0; t < 16; ++t) { best[t] = 3.4e38f; bidx[t] = 0; }

    auto stageA = [&](const f16* rowbase, int koff, char* unit) {
        #pragma unroll
        for (int q = 0; q < 2; ++q) {
            const int r = w * 32 + q * 16 + lq;
            gload_lds16(rowbase + (size_t)r * DIM + koff + gsw * 8,
                        unit + w * 2048 + q * 1024 + lane * 16);
        }
    };
    auto stageB = [&](int tileBase, int koff, char* unitH, char* unitL) {
        #pragma unroll
        for (int q = 0; q < 2; ++q) {
            const int r = w * 32 + q * 16 + lq;
            const int pr = cmap[tileBase + r];
            gload_lds16(eh + (size_t)pr * DIM + koff + gsw * 8,
                        unitH + w * 2048 + q * 1024 + lane * 16);
            gload_lds16(el + (size_t)pr * DIM + koff + gsw * 8,
                        unitL + w * 2048 + q * 1024 + lane * 16);
        }
    };

    ((f32x4*)e2s)[tid] = ((const f32x4*)ce2)[tid];
    stageA(xh + (size_t)row0 * DIM, 0, lds + OFF_AH);
    stageA(xl + (size_t)row0 * DIM, 0, lds + OFF_AL);
    stageB(0, 0, lds + OFF_BH, lds + OFF_BL);

    for (int cc = 0; cc < ncc; ++cc) {
        char* buf  = lds + (cc & 1) * 65536;
        char* nbuf = lds + ((cc + 1) & 1) * 65536;
        const int ct = cc >> 3, sd = cc & 7;
        const int nn = cc + 1;
        const int nct = nn >> 3, nsd = nn & 7;
        const bool more = (nn < ncc);

        if (sd == 0) {
            #pragma unroll
            for (int i = 0; i < 4; ++i)
                #pragma unroll
                for (int j = 0; j < 8; ++j)
                    acc[i][j] = (f32x4){0.f, 0.f, 0.f, 0.f};
        }

        asm volatile("s_waitcnt vmcnt(0)" ::: "memory");
        __builtin_amdgcn_s_barrier();
        __builtin_amdgcn_sched_barrier(0);

        // reads FIRST: ah + bh, pinned before stage
        f16x8 ah[4], al[4], bh[8], bl[8];
        #pragma unroll
        for (int i = 0; i < 4; ++i)
            ah[i] = *(const f16x8*)(buf + OFF_AH + (wm * 64 + i * 16 + l15) * 64 + rslot);
        #pragma unroll
        for (int j = 0; j < 8; ++j)
            bh[j] = *(const f16x8*)(buf + OFF_BH + (wn * 128 + j * 16 + l15) * 64 + rslot);
        __builtin_amdgcn_sched_barrier(0);

        // stage next chunk (latency hides under the MFMA window below)
        if (more) {
            stageA(xh + (size_t)row0 * DIM, nsd * 32, nbuf + OFF_AH);
            stageA(xl + (size_t)row0 * DIM, nsd * 32, nbuf + OFF_AL);
            stageB(nct * 256, nsd * 32, nbuf + OFF_BH, nbuf + OFF_BL);
        }

        // MFMA pass 1: ah * bh
        #pragma unroll
        for (int i = 0; i < 4; ++i)
            #pragma unroll
            for (int j = 0; j < 8; ++j)
                acc[i][j] = MFMA16(ah[i], bh[j], acc[i][j]);

        // pass 2: al * bh
        #pragma unroll
        for (int i = 0; i < 4; ++i)
            al[i] = *(const f16x8*)(buf + OFF_AL + (wm * 64 + i * 16 + l15) * 64 + rslot);
        #pragma unroll
        for (int i = 0; i < 4; ++i)
            #pragma unroll
            for (int j = 0; j < 8; ++j)
                acc[i][j] = MFMA16(al[i], bh[j], acc[i][j]);

        // pass 3: ah * bl
        #pragma unroll
        for (int j = 0; j < 8; ++j)
            bl[j] = *(const f16x8*)(buf + OFF_BL + (wn * 128 + j * 16 + l15) * 64 + rslot);
        #pragma unroll
        for (int i = 0; i < 4; ++i)
            #pragma unroll
            for (int j = 0; j < 8; ++j)
                acc[i][j] = MFMA16(ah[i], bl[j], acc[i][j]);

        if (sd == 7) {
            const int cbase = ct * 256 + wn * 128;
            #pragma unroll
            for (int j = 0; j < 8; ++j) {
                const int col = cbase + j * 16 + l15;
                const float e2v = e2s[col];
                #pragma unroll
                for (int i = 0; i < 4; ++i)
                    #pragma unroll
                    for (int r = 0; r < 4; ++r) {
                        float m = fmaf(-2.0f, acc[i][j][r], e2v);
                        const int tt_ = i * 4 + r;
                        if (m < best[tt_]) { best[tt_] = m; bidx[tt_] = col; }
                    }
            }
        }
    }

    __syncthreads();
    float* rv = (float*)lds;
    int*   ri = (int*)(lds + 4096);
    #pragma unroll
    for (int tt_ = 0; tt_ < 16; ++tt_) {
        float v = best[tt_];
        int  ix = bidx[tt_];
        #pragma unroll
        for (int m = 1; m <= 8; m <<= 1) {
            float ov = __shfl_xor(v, m, 64);
            int  oix = __shfl_xor(ix, m, 64);
            if (ov < v || (ov == v && oix < ix)) { v = ov; ix = oix; }
        }
        if (l15 == 0) {
            const int rl = wm * 64 + (tt_ >> 2) * 16 + l4 * 4 + (tt_ & 3);
            rv[rl * 2 + wn] = v;
            ri[rl * 2 + wn] = ix;
        }
    }
    __syncthreads();
    if (tid < 256) {
        float v0 = rv[tid * 2], v1 = rv[tid * 2 + 1];
        int   i0 = ri[tid * 2], i1 = ri[tid * 2 + 1];
        int ibc = (v1 < v0 || (v1 == v0 && i1 < i0)) ? i1 : i0;
        int ib = cmap[ibc];
        flat_ind[row0 + tid] = ib;
        unsigned long long pending = ~0ULL;
        while (pending) {
            int leader = __ffsll((long long)pending) - 1;
            int lind = __shfl(ib, leader, 64);
            unsigned long long same = __ballot(ib == lind);
            if ((tid & 63) == leader) atomicAdd(&cnt[lind], (int)__popcll(same));
            pending &= ~same;
        }
    }
}

// ---------------------------------------------------------------------------
// scan: exclusive prefix sum over 2048 counts -> offsets, cursor
// ---------------------------------------------------------------------------
__global__ __launch_bounds__(256) void scan_kernel(
    const int* __restrict__ cnt, int* __restrict__ offs, int* __restrict__ cursor)
{
    __shared__ int ps[256];
    const int t = threadIdx.x;
    int pre[8], s = 0;
    #pragma unroll
    for (int j = 0; j < 8; ++j) { pre[j] = s; s += cnt[t * 8 + j]; }
    ps[t] = s;
    __syncthreads();
    for (int off = 1; off < 256; off <<= 1) {
        int v = (t >= off) ? ps[t - off] : 0;
        __syncthreads();
        ps[t] += v;
        __syncthreads();
    }
    int ex = (t > 0) ? ps[t - 1] : 0;
    #pragma unroll
    for (int j = 0; j < 8; ++j) {
        offs[t * 8 + j]   = ex + pre[j];
        cursor[t * 8 + j] = ex + pre[j];
    }
}

// ---------------------------------------------------------------------------
// assign: counting-sort placement with wave-aggregated cursor atomics.
// ---------------------------------------------------------------------------
__global__ __launch_bounds__(256) void assign_kernel(
    const int* __restrict__ flat_ind, int* __restrict__ cursor,
    int* __restrict__ rowlist, int* __restrict__ codesorted)
{
    const int i    = blockIdx.x * 256 + threadIdx.x;
    const int lane = threadIdx.x & 63;
    const int ind  = flat_ind[i];
    int pos = 0;
    unsigned long long pending = ~0ULL;
    while (pending) {
        int leader = __ffsll((long long)pending) - 1;
        int lind = __shfl(ind, leader, 64);
        unsigned long long same = __ballot(ind == lind);
        if (ind == lind) {
            int base = 0;
            if (lane == leader) base = atomicAdd(&cursor[lind], (int)__popcll(same));
            base = __shfl(base, leader, 64);
            pos = base + (int)__popcll(same & ((1ULL << lane) - 1ULL));
        }
        pending &= ~same;
    }
    rowlist[pos] = i;
    codesorted[pos] = ind;
}

// ---------------------------------------------------------------------------
// fused codesum + quantize (round-12 arrangement, best measured).
// ---------------------------------------------------------------------------
__global__ __launch_bounds__(256) void codesum_quant_kernel(
    const float* __restrict__ x, const int* __restrict__ rowlist,
    const int* __restrict__ codesorted, float* __restrict__ sums, int nc,
    const float* __restrict__ embed, const int* __restrict__ flat_ind,
    float* __restrict__ out_q, float* __restrict__ out_ind_f, int N)
{
    if ((int)blockIdx.x < nc) {
        const int p0 = blockIdx.x * 64;
        __shared__ int rows[64], codes[64];
        if (threadIdx.x < 64) {
            rows[threadIdx.x]  = rowlist[p0 + threadIdx.x];
            codes[threadIdx.x] = codesorted[p0 + threadIdx.x];
        }
        __syncthreads();
        const int d = threadIdx.x;
        float acc = 0.f;
        int cur = codes[0];
        #pragma unroll 4
        for (int r = 0; r < 64; ++r) {
            const int c = codes[r];
            if (c != cur) {
                atomicAdd(&sums[(size_t)cur * DIM + d], acc);
                acc = 0.f; cur = c;
            }
            acc += x[(size_t)rows[r] * DIM + d];
        }
        atomicAdd(&sums[(size_t)cur * DIM + d], acc);
    } else {
        int i = (blockIdx.x - nc) * 256 + threadIdx.x;   // over N*64 float4s
        int row = i >> 6, c4 = i & 63;
        int ind = flat_ind[row];
        ((f32x4*)out_q)[i] = ((const f32x4*)embed)[ind * 64 + c4];
        if (i < N) out_ind_f[i] = (float)flat_ind[i];
    }
}

// ---------------------------------------------------------------------------
// finalize: EMA update outputs
// ---------------------------------------------------------------------------
__global__ __launch_bounds__(256) void finalize_kernel(
    const float* __restrict__ embed_sum, const float* __restrict__ usage,
    const float* __restrict__ sums, const int* __restrict__ cnt,
    float* __restrict__ out_usage, float* __restrict__ out_es)
{
    const int k = blockIdx.x, d = threadIdx.x;
    out_es[k * DIM + d] = embed_sum[k * DIM + d] * DECAYF + sums[k * DIM + d] * (1.0f - DECAYF);
    if (d == 0)
        out_usage[k] = usage[k] * DECAYF + (float)cnt[k] * (1.0f - DECAYF);
}

extern "C" void kernel_launch(void* const* d_in, const int* in_sizes, int n_in,
                              void* d_out, int out_size, void* d_ws, size_t ws_size,
                              hipStream_t stream)
{
    const float* hs        = (const float*)d_in[0];
    const float* embed_sum = (const float*)d_in[1];
    const float* usage     = (const float*)d_in[2];
    const int N = in_sizes[0] / DIM;   // 65536

    float* ws_f      = (float*)d_ws;
    float* embed     = ws_f;                         // K*D f32
    float* e2        = embed + KCODES * DIM;         // K
    float* sums      = e2 + KCODES;                  // K*D f32 (zeroed in prep)
    int*   cnt       = (int*)(sums + KCODES * DIM);  // K       (zeroed in prep)
    unsigned* pmax   = (unsigned*)(cnt + KCODES);    // 64  (memset 0)
    int*   cidx      = (int*)(pmax + 64);            // 8
    float* e2c       = (float*)(cidx + 8);           // 8
    f16*   eh        = (f16*)(e2c + 8);              // K*D f16
    f16*   el        = eh + KCODES * DIM;            // K*D f16
    float* ce2       = (float*)(el + KCODES * DIM);  // K
    int*   cmap      = (int*)(ce2 + KCODES);         // K
    int*   meta      = cmap + KCODES;                // 16
    int*   offs      = meta + 16;                    // K
    int*   cursor    = offs + KCODES;                // K
    int*   rowlist   = cursor + KCODES;              // N
    int*   codesorted= rowlist + N;                  // N
    int*   flat_ind  = codesorted + N;               // N

    float* out_q     = (float*)d_out;                // N*D
    float* out_ind   = out_q + (size_t)N * DIM;      // N
    float* out_usage = out_ind + N;                  // K
    float* out_es    = out_usage + KCODES;           // K*D

    // xh/xl live in the out_q region (exactly N*D*4B); dead after argmin,
    // codesum_quant overwrites out_q afterwards.
    f16* xh = (f16*)out_q;
    f16* xl = xh + (size_t)N * DIM;

    hipMemsetAsync(pmax, 0, 64 * sizeof(unsigned), stream);

    prep_kernel<<<2 * KCODES, 256, 0, stream>>>(embed_sum, usage, embed, eh, el, e2,
                                                sums, cnt);
    pick_kernel<<<1, 256, 0, stream>>>(e2, cidx, e2c);
    const int nsplit = N * DIM / 8 / 256;            // 8192
    splitx_kernel<<<nsplit, 256, 0, stream>>>(hs, xh, xl, embed, cidx, e2c, pmax);
    compactA_kernel<<<1, 256, 0, stream>>>(e2, pmax, ce2, cmap, meta);
    argmin_kernel<<<N / 256, 512, 0, stream>>>(xh, xl, eh, el, ce2, cmap, meta,
                                               flat_ind, cnt);
    scan_kernel<<<1, 256, 0, stream>>>(cnt, offs, cursor);
    assign_kernel<<<N / 256, 256, 0, stream>>>(flat_ind, cursor, rowlist, codesorted);
    const int nc = N / 64;                           // 1024
    const int nq = N * DIM / 4 / 256;                // 16384
    codesum_quant_kernel<<<nc + nq, 256, 0, stream>>>(
        hs, rowlist, codesorted, sums, nc, embed, flat_ind, out_q, out_ind, N);
    finalize_kernel<<<KCODES, 256, 0, stream>>>(embed_sum, usage, sums, cnt,
                                                out_usage, out_es);
}

// Round 16
// 261.061 us; speedup vs baseline: 1.0590x; 1.0110x over previous
//
#include <hip/hip_runtime.h>

#define EPSF 1e-5f
#define DECAYF 0.99f
#define KCODES 2048
#define DIM 256

typedef _Float16 f16;
typedef f16 f16x8 __attribute__((ext_vector_type(8)));
typedef float f32x4 __attribute__((ext_vector_type(4)));
typedef unsigned long long u64;

#define MFMA16(A, B, C) __builtin_amdgcn_mfma_f32_16x16x32_f16(A, B, C, 0, 0, 0)

#define OFF_AH 0
#define OFF_AL 16384
#define OFF_BH 32768
#define OFF_BL 49152

__device__ __forceinline__ void gload_lds16(const void* g, void* l) {
    __builtin_amdgcn_global_load_lds(
        (const __attribute__((address_space(1))) void*)g,
        (__attribute__((address_space(3))) void*)l, 16, 0, 0);
}

// ---------------------------------------------------------------------------
// prep: embed = embed_sum/clamp(usage); e2; saturated f16 split; publishes
// per-residue-class min-e2 candidates as packed u64 keys (atomicMax on
// cslots[k&63], key = (~u(-e2))<<32 | k — larger key = smaller e2).
// blocks [K,2K) zero sums/cnt + pmax (all consumed by later dispatches).
// ---------------------------------------------------------------------------
__global__ __launch_bounds__(256) void prep_kernel(
    const float* __restrict__ embed_sum, const float* __restrict__ usage,
    float* __restrict__ embed, f16* __restrict__ eh, f16* __restrict__ el,
    float* __restrict__ e2, u64* __restrict__ cslots,
    float* __restrict__ sums, int* __restrict__ cnt, unsigned* __restrict__ pmax)
{
    if ((int)blockIdx.x < KCODES) {
        int k = blockIdx.x;
        int d = threadIdx.x;
        float inv = 1.0f / fmaxf(usage[k], EPSF);
        float e = embed_sum[k * DIM + d] * inv;
        embed[k * DIM + d] = e;
        float ec = fminf(fmaxf(e, -65000.0f), 65000.0f);
        f16 h = (f16)ec;
        f16 l = (f16)(ec - (float)h);
        eh[k * DIM + d] = h;
        el[k * DIM + d] = l;
        float sq = e * e;
        #pragma unroll
        for (int off = 32; off > 0; off >>= 1) sq += __shfl_down(sq, off, 64);
        __shared__ float ws[4];
        if ((threadIdx.x & 63) == 0) ws[threadIdx.x >> 6] = sq;
        __syncthreads();
        if (threadIdx.x == 0) {
            float s = ws[0] + ws[1] + ws[2] + ws[3];
            e2[k] = s;
            u64 key = ((u64)(~__float_as_uint(-s)) << 32) | (unsigned)k;
            atomicMax(&cslots[k & 63], key);
        }
    } else {
        int k = blockIdx.x - KCODES;
        sums[k * DIM + threadIdx.x] = 0.f;
        if (threadIdx.x == 0) cnt[k] = 0;
        if (k == 0 && threadIdx.x < 64) pmax[threadIdx.x] = 0u;
    }
}

// ---------------------------------------------------------------------------
// splitx: xh/xl split + per-row exact prune key:
//   key = (||x|| + min_{r<8} d(x,c_r))^2   (winner bound, rigorous for ANY
//   candidate set). Candidates: 8 largest packed keys from the 64 cslots
//   (selected inline by wave 0 — no separate pick dispatch).
// 64-slot partial atomicMax for the block maxima.
// ---------------------------------------------------------------------------
__global__ __launch_bounds__(256) void splitx_kernel(
    const float* __restrict__ x, f16* __restrict__ xh, f16* __restrict__ xl,
    const float* __restrict__ embed, const u64* __restrict__ cslots,
    unsigned* __restrict__ pmax)
{
    __shared__ float ecs[8 * 256];
    __shared__ float e2cs[8];
    __shared__ int   cidxs[8];
    __shared__ float wmax[4];
    const int t = threadIdx.x;

    // ---- inline candidate selection (wave 0): top-8 keys of 64 slots
    if (t < 64) {
        u64 key = cslots[t];
        #pragma unroll
        for (int r = 0; r < 8; ++r) {
            u64 m = key;
            #pragma unroll
            for (int off = 1; off <= 32; off <<= 1) {
                u64 o = __shfl_xor(m, off, 64);
                m = (o > m) ? o : m;
            }
            if (t == 0) {
                cidxs[r] = (int)(m & 0xFFFFFFFFu);
                e2cs[r]  = -__uint_as_float(~(unsigned)(m >> 32));
            }
            if (key == m) key = 0;   // keys unique (index packed) -> one lane clears
        }
    }
    __syncthreads();
    #pragma unroll
    for (int j = 0; j < 8; ++j) {
        int idx = t * 8 + j;  // 0..2047
        ecs[idx] = embed[(size_t)cidxs[idx >> 8] * DIM + (idx & 255)];
    }
    __syncthreads();

    int i = blockIdx.x * 256 + t;
    f32x4 v0 = ((const f32x4*)x)[2 * i];
    f32x4 v1 = ((const f32x4*)x)[2 * i + 1];
    float xv[8];
    #pragma unroll
    for (int q = 0; q < 4; ++q) { xv[q] = v0[q]; xv[q + 4] = v1[q]; }
    f16x8 h, l;
    float p = 0.f;
    #pragma unroll
    for (int j = 0; j < 8; ++j) {
        f16 hh = (f16)xv[j]; h[j] = hh; l[j] = (f16)(xv[j] - (float)hh);
        p += xv[j] * xv[j];
    }
    ((f16x8*)xh)[i] = h;
    ((f16x8*)xl)[i] = l;

    const int base = (t & 31) * 8;
    float dot[8];
    #pragma unroll
    for (int r = 0; r < 8; ++r) {
        const float* er = &ecs[r * 256 + base];
        float d = 0.f;
        #pragma unroll
        for (int j = 0; j < 8; ++j) d = fmaf(xv[j], er[j], d);
        dot[r] = d;
    }
    // butterfly over the 32 lanes of each x-row
    #pragma unroll
    for (int m = 1; m <= 16; m <<= 1) {
        p += __shfl_xor(p, m, 64);
        #pragma unroll
        for (int r = 0; r < 8; ++r) dot[r] += __shfl_xor(dot[r], m, 64);
    }
    float dmin2 = 3.4e38f;
    #pragma unroll
    for (int r = 0; r < 8; ++r) {
        float d2 = fmaxf(fmaf(-2.f, dot[r], p) + e2cs[r], 0.f);
        dmin2 = fminf(dmin2, d2);
    }
    float key = sqrtf(p) + sqrtf(dmin2);
    key = key * key;
    #pragma unroll
    for (int m = 1; m <= 32; m <<= 1) key = fmaxf(key, __shfl_xor(key, m, 64));
    if ((t & 63) == 0) wmax[t >> 6] = key;
    __syncthreads();
    if (t == 0) {
        float bm = fmaxf(fmaxf(wmax[0], wmax[1]), fmaxf(wmax[2], wmax[3]));
        atomicMax(&pmax[blockIdx.x & 63], __float_as_uint(bm) | 0x80000000u);
    }
}

// ---------------------------------------------------------------------------
// compactA: T = max key (64-slot reduce) with fp slop; STABLE compaction.
// ---------------------------------------------------------------------------
__global__ __launch_bounds__(256) void compactA_kernel(
    const float* __restrict__ e2, const unsigned* __restrict__ pmax,
    float* __restrict__ ce2, int* __restrict__ cmap, int* __restrict__ meta)
{
    __shared__ int ps[256];
    __shared__ float sT;
    const int t = threadIdx.x;
    if (t < 64) {
        unsigned km = pmax[t];
        #pragma unroll
        for (int m = 1; m <= 32; m <<= 1)
            km = max(km, (unsigned)__shfl_xor((int)km, m, 64));
        if (t == 0) {
            float mx = __uint_as_float(km & 0x7FFFFFFFu);
            sT = mx * 1.0005f + 1.0f;
        }
    }
    __syncthreads();
    const float T = sT;
    int flag[8], pre[8], s = 0;
    float ev[8];
    #pragma unroll
    for (int j = 0; j < 8; ++j) {
        ev[j] = e2[t * 8 + j];
        flag[j] = (ev[j] <= T) ? 1 : 0;
        pre[j] = s; s += flag[j];
    }
    ps[t] = s;
    __syncthreads();
    for (int off = 1; off < 256; off <<= 1) {
        int v = (t >= off) ? ps[t - off] : 0;
        __syncthreads();
        ps[t] += v;
        __syncthreads();
    }
    const int ex = (t > 0) ? ps[t - 1] : 0;
    const int kp = ps[255];
    #pragma unroll
    for (int j = 0; j < 8; ++j) {
        const int k = t * 8 + j;
        if (flag[j]) {
            const int p = ex + pre[j];
            ce2[p] = ev[j];
            cmap[p] = k;
        }
    }
    for (int j = t; j < KCODES; j += 256)
        if (j >= kp) { ce2[j] = 3.4e38f; cmap[j] = 0; }
    if (t == 0) { meta[0] = kp; meta[1] = (kp + 255) & ~255; }
}

// ---------------------------------------------------------------------------
// argmin over the pruned codebook (round-12 version: best measured).
// ---------------------------------------------------------------------------
__global__ __launch_bounds__(512, 2) void argmin_kernel(
    const f16* __restrict__ xh, const f16* __restrict__ xl,
    const f16* __restrict__ eh, const f16* __restrict__ el,
    const float* __restrict__ ce2, const int* __restrict__ cmap,
    const int* __restrict__ meta, int* __restrict__ flat_ind, int* __restrict__ cnt)
{
    __shared__ __align__(1024) char lds[2 * 65536 + 8192];
    float* e2s = (float*)(lds + 131072);

    const int ncc = meta[1] >> 5;
    const int tid  = threadIdx.x;
    const int w    = tid >> 6, lane = tid & 63;
    const int l15  = lane & 15, l4 = lane >> 4;
    const int wm   = w >> 1, wn = w & 1;
    const int row0 = blockIdx.x * 256;
    const int gsw  = (lane & 3) ^ ((lane >> 3) & 3);
    const int lq   = lane >> 2;
    const int rslot = (l4 ^ ((l15 >> 1) & 3)) * 16;

    f32x4 acc[4][8];
    float best[16];
    int   bidx[16];
    #pragma unroll
    for (int t = 0; t < 16; ++t) { best[t] = 3.4e38f; bidx[t] = 0; }

    auto stageA = [&](const f16* rowbase, int koff, char* unit) {
        #pragma unroll
        for (int q = 0; q < 2; ++q) {
            const int r = w * 32 + q * 16 + lq;
            gload_lds16(rowbase + (size_t)r * DIM + koff + gsw * 8,
                        unit + w * 2048 + q * 1024 + lane * 16);
        }
    };
    auto stageB = [&](int tileBase, int koff, char* unitH, char* unitL) {
        #pragma unroll
        for (int q = 0; q < 2; ++q) {
            const int r = w * 32 + q * 16 + lq;
            const int pr = cmap[tileBase + r];
            gload_lds16(eh + (size_t)pr * DIM + koff + gsw * 8,
                        unitH + w * 2048 + q * 1024 + lane * 16);
            gload_lds16(el + (size_t)pr * DIM + koff + gsw * 8,
                        unitL + w * 2048 + q * 1024 + lane * 16);
        }
    };

    ((f32x4*)e2s)[tid] = ((const f32x4*)ce2)[tid];
    stageA(xh + (size_t)row0 * DIM, 0, lds + OFF_AH);
    stageA(xl + (size_t)row0 * DIM, 0, lds + OFF_AL);
    stageB(0, 0, lds + OFF_BH, lds + OFF_BL);

    for (int cc = 0; cc < ncc; ++cc) {
        char* buf  = lds + (cc & 1) * 65536;
        char* nbuf = lds + ((cc + 1) & 1) * 65536;
        const int ct = cc >> 3, sd = cc & 7;
        const int nn = cc + 1;
        const int nct = nn >> 3, nsd = nn & 7;
        const bool more = (nn < ncc);

        if (sd == 0) {
            #pragma unroll
            for (int i = 0; i < 4; ++i)
                #pragma unroll
                for (int j = 0; j < 8; ++j)
                    acc[i][j] = (f32x4){0.f, 0.f, 0.f, 0.f};
        }

        asm volatile("s_waitcnt vmcnt(0)" ::: "memory");
        __builtin_amdgcn_s_barrier();
        __builtin_amdgcn_sched_barrier(0);

        // reads FIRST: ah + bh, pinned before stage
        f16x8 ah[4], al[4], bh[8], bl[8];
        #pragma unroll
        for (int i = 0; i < 4; ++i)
            ah[i] = *(const f16x8*)(buf + OFF_AH + (wm * 64 + i * 16 + l15) * 64 + rslot);
        #pragma unroll
        for (int j = 0; j < 8; ++j)
            bh[j] = *(const f16x8*)(buf + OFF_BH + (wn * 128 + j * 16 + l15) * 64 + rslot);
        __builtin_amdgcn_sched_barrier(0);

        // stage next chunk (latency hides under the MFMA window below)
        if (more) {
            stageA(xh + (size_t)row0 * DIM, nsd * 32, nbuf + OFF_AH);
            stageA(xl + (size_t)row0 * DIM, nsd * 32, nbuf + OFF_AL);
            stageB(nct * 256, nsd * 32, nbuf + OFF_BH, nbuf + OFF_BL);
        }

        // MFMA pass 1: ah * bh
        #pragma unroll
        for (int i = 0; i < 4; ++i)
            #pragma unroll
            for (int j = 0; j < 8; ++j)
                acc[i][j] = MFMA16(ah[i], bh[j], acc[i][j]);

        // pass 2: al * bh
        #pragma unroll
        for (int i = 0; i < 4; ++i)
            al[i] = *(const f16x8*)(buf + OFF_AL + (wm * 64 + i * 16 + l15) * 64 + rslot);
        #pragma unroll
        for (int i = 0; i < 4; ++i)
            #pragma unroll
            for (int j = 0; j < 8; ++j)
                acc[i][j] = MFMA16(al[i], bh[j], acc[i][j]);

        // pass 3: ah * bl
        #pragma unroll
        for (int j = 0; j < 8; ++j)
            bl[j] = *(const f16x8*)(buf + OFF_BL + (wn * 128 + j * 16 + l15) * 64 + rslot);
        #pragma unroll
        for (int i = 0; i < 4; ++i)
            #pragma unroll
            for (int j = 0; j < 8; ++j)
                acc[i][j] = MFMA16(ah[i], bl[j], acc[i][j]);

        if (sd == 7) {
            const int cbase = ct * 256 + wn * 128;
            #pragma unroll
            for (int j = 0; j < 8; ++j) {
                const int col = cbase + j * 16 + l15;
                const float e2v = e2s[col];
                #pragma unroll
                for (int i = 0; i < 4; ++i)
                    #pragma unroll
                    for (int r = 0; r < 4; ++r) {
                        float m = fmaf(-2.0f, acc[i][j][r], e2v);
                        const int tt_ = i * 4 + r;
                        if (m < best[tt_]) { best[tt_] = m; bidx[tt_] = col; }
                    }
            }
        }
    }

    __syncthreads();
    float* rv = (float*)lds;
    int*   ri = (int*)(lds + 4096);
    #pragma unroll
    for (int tt_ = 0; tt_ < 16; ++tt_) {
        float v = best[tt_];
        int  ix = bidx[tt_];
        #pragma unroll
        for (int m = 1; m <= 8; m <<= 1) {
            float ov = __shfl_xor(v, m, 64);
            int  oix = __shfl_xor(ix, m, 64);
            if (ov < v || (ov == v && oix < ix)) { v = ov; ix = oix; }
        }
        if (l15 == 0) {
            const int rl = wm * 64 + (tt_ >> 2) * 16 + l4 * 4 + (tt_ & 3);
            rv[rl * 2 + wn] = v;
            ri[rl * 2 + wn] = ix;
        }
    }
    __syncthreads();
    if (tid < 256) {
        float v0 = rv[tid * 2], v1 = rv[tid * 2 + 1];
        int   i0 = ri[tid * 2], i1 = ri[tid * 2 + 1];
        int ibc = (v1 < v0 || (v1 == v0 && i1 < i0)) ? i1 : i0;
        int ib = cmap[ibc];
        flat_ind[row0 + tid] = ib;
        unsigned long long pending = ~0ULL;
        while (pending) {
            int leader = __ffsll((long long)pending) - 1;
            int lind = __shfl(ib, leader, 64);
            unsigned long long same = __ballot(ib == lind);
            if ((tid & 63) == leader) atomicAdd(&cnt[lind], (int)__popcll(same));
            pending &= ~same;
        }
    }
}

// ---------------------------------------------------------------------------
// scan: exclusive prefix sum over 2048 counts -> offsets, cursor
// ---------------------------------------------------------------------------
__global__ __launch_bounds__(256) void scan_kernel(
    const int* __restrict__ cnt, int* __restrict__ offs, int* __restrict__ cursor)
{
    __shared__ int ps[256];
    const int t = threadIdx.x;
    int pre[8], s = 0;
    #pragma unroll
    for (int j = 0; j < 8; ++j) { pre[j] = s; s += cnt[t * 8 + j]; }
    ps[t] = s;
    __syncthreads();
    for (int off = 1; off < 256; off <<= 1) {
        int v = (t >= off) ? ps[t - off] : 0;
        __syncthreads();
        ps[t] += v;
        __syncthreads();
    }
    int ex = (t > 0) ? ps[t - 1] : 0;
    #pragma unroll
    for (int j = 0; j < 8; ++j) {
        offs[t * 8 + j]   = ex + pre[j];
        cursor[t * 8 + j] = ex + pre[j];
    }
}

// ---------------------------------------------------------------------------
// assign: counting-sort placement with wave-aggregated cursor atomics.
// ---------------------------------------------------------------------------
__global__ __launch_bounds__(256) void assign_kernel(
    const int* __restrict__ flat_ind, int* __restrict__ cursor,
    int* __restrict__ rowlist, int* __restrict__ codesorted)
{
    const int i    = blockIdx.x * 256 + threadIdx.x;
    const int lane = threadIdx.x & 63;
    const int ind  = flat_ind[i];
    int pos = 0;
    unsigned long long pending = ~0ULL;
    while (pending) {
        int leader = __ffsll((long long)pending) - 1;
        int lind = __shfl(ind, leader, 64);
        unsigned long long same = __ballot(ind == lind);
        if (ind == lind) {
            int base = 0;
            if (lane == leader) base = atomicAdd(&cursor[lind], (int)__popcll(same));
            base = __shfl(base, leader, 64);
            pos = base + (int)__popcll(same & ((1ULL << lane) - 1ULL));
        }
        pending &= ~same;
    }
    rowlist[pos] = i;
    codesorted[pos] = ind;
}

// ---------------------------------------------------------------------------
// fused codesum + quantize (round-12 arrangement, best measured).
// ---------------------------------------------------------------------------
__global__ __launch_bounds__(256) void codesum_quant_kernel(
    const float* __restrict__ x, const int* __restrict__ rowlist,
    const int* __restrict__ codesorted, float* __restrict__ sums, int nc,
    const float* __restrict__ embed, const int* __restrict__ flat_ind,
    float* __restrict__ out_q, float* __restrict__ out_ind_f, int N)
{
    if ((int)blockIdx.x < nc) {
        const int p0 = blockIdx.x * 64;
        __shared__ int rows[64], codes[64];
        if (threadIdx.x < 64) {
            rows[threadIdx.x]  = rowlist[p0 + threadIdx.x];
            codes[threadIdx.x] = codesorted[p0 + threadIdx.x];
        }
        __syncthreads();
        const int d = threadIdx.x;
        float acc = 0.f;
        int cur = codes[0];
        #pragma unroll 4
        for (int r = 0; r < 64; ++r) {
            const int c = codes[r];
            if (c != cur) {
                atomicAdd(&sums[(size_t)cur * DIM + d], acc);
                acc = 0.f; cur = c;
            }
            acc += x[(size_t)rows[r] * DIM + d];
        }
        atomicAdd(&sums[(size_t)cur * DIM + d], acc);
    } else {
        int i = (blockIdx.x - nc) * 256 + threadIdx.x;   // over N*64 float4s
        int row = i >> 6, c4 = i & 63;
        int ind = flat_ind[row];
        ((f32x4*)out_q)[i] = ((const f32x4*)embed)[ind * 64 + c4];
        if (i < N) out_ind_f[i] = (float)flat_ind[i];
    }
}

// ---------------------------------------------------------------------------
// finalize: EMA update outputs
// ---------------------------------------------------------------------------
__global__ __launch_bounds__(256) void finalize_kernel(
    const float* __restrict__ embed_sum, const float* __restrict__ usage,
    const float* __restrict__ sums, const int* __restrict__ cnt,
    float* __restrict__ out_usage, float* __restrict__ out_es)
{
    const int k = blockIdx.x, d = threadIdx.x;
    out_es[k * DIM + d] = embed_sum[k * DIM + d] * DECAYF + sums[k * DIM + d] * (1.0f - DECAYF);
    if (d == 0)
        out_usage[k] = usage[k] * DECAYF + (float)cnt[k] * (1.0f - DECAYF);
}

extern "C" void kernel_launch(void* const* d_in, const int* in_sizes, int n_in,
                              void* d_out, int out_size, void* d_ws, size_t ws_size,
                              hipStream_t stream)
{
    const float* hs        = (const float*)d_in[0];
    const float* embed_sum = (const float*)d_in[1];
    const float* usage     = (const float*)d_in[2];
    const int N = in_sizes[0] / DIM;   // 65536

    float* ws_f      = (float*)d_ws;
    float* embed     = ws_f;                         // K*D f32
    float* e2        = embed + KCODES * DIM;         // K
    float* sums      = e2 + KCODES;                  // K*D f32 (zeroed in prep)
    int*   cnt       = (int*)(sums + KCODES * DIM);  // K       (zeroed in prep)
    unsigned* pmax   = (unsigned*)(cnt + KCODES);    // 64 u32  (zeroed in prep)
    u64*   cslots    = (u64*)(pmax + 64);            // 64 u64  (memset 0) [8B-aligned]
    f16*   eh        = (f16*)(cslots + 64);          // K*D f16
    f16*   el        = eh + KCODES * DIM;            // K*D f16
    float* ce2       = (float*)(el + KCODES * DIM);  // K
    int*   cmap      = (int*)(ce2 + KCODES);         // K
    int*   meta      = cmap + KCODES;                // 16
    int*   offs      = meta + 16;                    // K
    int*   cursor    = offs + KCODES;                // K
    int*   rowlist   = cursor + KCODES;              // N
    int*   codesorted= rowlist + N;                  // N
    int*   flat_ind  = codesorted + N;               // N

    float* out_q     = (float*)d_out;                // N*D
    float* out_ind   = out_q + (size_t)N * DIM;      // N
    float* out_usage = out_ind + N;                  // K
    float* out_es    = out_usage + KCODES;           // K*D

    // xh/xl live in the out_q region (exactly N*D*4B); dead after argmin,
    // codesum_quant overwrites out_q afterwards.
    f16* xh = (f16*)out_q;
    f16* xl = xh + (size_t)N * DIM;

    hipMemsetAsync(cslots, 0, 64 * sizeof(u64), stream);

    prep_kernel<<<2 * KCODES, 256, 0, stream>>>(embed_sum, usage, embed, eh, el, e2,
                                                cslots, sums, cnt, pmax);
    const int nsplit = N * DIM / 8 / 256;            // 8192
    splitx_kernel<<<nsplit, 256, 0, stream>>>(hs, xh, xl, embed, cslots, pmax);
    compactA_kernel<<<1, 256, 0, stream>>>(e2, pmax, ce2, cmap, meta);
    argmin_kernel<<<N / 256, 512, 0, stream>>>(xh, xl, eh, el, ce2, cmap, meta,
                                               flat_ind, cnt);
    scan_kernel<<<1, 256, 0, stream>>>(cnt, offs, cursor);
    assign_kernel<<<N / 256, 256, 0, stream>>>(flat_ind, cursor, rowlist, codesorted);
    const int nc = N / 64;                           // 1024
    const int nq = N * DIM / 4 / 256;                // 16384
    codesum_quant_kernel<<<nc + nq, 256, 0, stream>>>(
        hs, rowlist, codesorted, sums, nc, embed, flat_ind, out_q, out_ind, N);
    finalize_kernel<<<KCODES, 256, 0, stream>>>(embed_sum, usage, sums, cnt,
                                                out_usage, out_es);
}